// Round 2
// baseline (143.500 us; speedup 1.0000x reference)
//
#include <hip/hip_runtime.h>
#include <math.h>

#define B 2
#define C 64
#define N 4096
#define O3 384
#define HID 128
#define NH 4
#define DH 32
#define TP 32          /* positions per block (K1/K3): B*(N/TP)=256 blocks = 1/CU */
#define JC 128
#define NCH (N / JC)   /* 32 */

#define SCALE 0.17677669529663687f /* 32^-0.5 */

// ---------------- K1: RMSNorm (dim=c) + 1x1-conv QKV projection ----------------
// grid: B * (N/TP) = 256 blocks of 256. Each block: TP positions, all 64 channels.
__global__ __launch_bounds__(256) void k1_rmsnorm_qkv(
    const float* __restrict__ x, const float* __restrict__ g,
    const float* __restrict__ wqkv, float* __restrict__ qkv)
{
    __shared__ float xs[C][TP + 1];
    __shared__ float part[8][TP];
    __shared__ float scale_s[TP];
    __shared__ float gs[C];

    const int t = threadIdx.x;
    const int bx = blockIdx.x;
    const int b = bx / (N / TP);
    const int p0 = (bx % (N / TP)) * TP;

    const float* xb = x + (size_t)b * C * N;
    for (int idx = t; idx < C * TP; idx += 256) {
        int c = idx >> 5, p = idx & (TP - 1);
        xs[c][p] = xb[(size_t)c * N + p0 + p];
    }
    if (t < C) gs[t] = g[t];
    __syncthreads();

    {
        int p = t & (TP - 1), cg = t >> 5; /* 8 groups of 8 channels */
        float s = 0.f;
        #pragma unroll
        for (int c = 0; c < 8; ++c) {
            float v_ = xs[cg * 8 + c][p];
            s += v_ * v_;
        }
        part[cg][p] = s;
    }
    __syncthreads();
    if (t < TP) {
        float ss = 0.f;
        #pragma unroll
        for (int gIdx = 0; gIdx < 8; ++gIdx) ss += part[gIdx][t];
        float nrm = sqrtf(ss);
        scale_s[t] = 8.0f / fmaxf(nrm, 1e-12f); /* sqrt(C)=8, torch eps */
    }
    __syncthreads();
    for (int idx = t; idx < C * TP; idx += 256) {
        int c = idx >> 5, p = idx & (TP - 1);
        xs[c][p] *= scale_s[p] * gs[c];
    }
    __syncthreads();

    // qkv[o][p] = sum_c W[o][c] * xn[c][p]; thread-group (t>>5) handles 48 outputs
    const int p = t & (TP - 1);
    const int o0 = (t >> 5) * 48;
    float* outb = qkv + (size_t)b * O3 * N + p0 + p;
    for (int o = o0; o < o0 + 48; ++o) {
        const float4* wr = (const float4*)(wqkv + (size_t)o * C);
        float acc = 0.f;
        #pragma unroll
        for (int c4 = 0; c4 < 16; ++c4) {
            float4 w4 = wr[c4];
            int c = c4 * 4;
            acc += w4.x * xs[c][p] + w4.y * xs[c + 1][p]
                 + w4.z * xs[c + 2][p] + w4.w * xs[c + 3][p];
        }
        if (o < HID) acc *= SCALE; /* q pre-scaled */
        outb[(size_t)o * N] = acc;
    }
}

// ---------------- K2: partial M = K V^T per (b, h, j-chunk) ----------------
// grid: B*NH*NCH = 256 blocks of 256. Thread t -> M[e][d0..d0+3], e=t>>3, d0=(t&7)*4.
__global__ __launch_bounds__(256) void k2_kv_outer(
    const float* __restrict__ qkv, float* __restrict__ mpart)
{
    __shared__ float ks[DH][JC + 1];
    __shared__ float vs[DH][JC + 1];
    const int t = threadIdx.x;
    const int bx = blockIdx.x;
    const int b = bx / (NH * NCH);
    const int rem = bx % (NH * NCH);
    const int h = rem / NCH, ch = rem % NCH;
    const int j0 = ch * JC;

    const float* kb = qkv + (size_t)b * O3 * N + (size_t)(HID + h * DH) * N + j0;
    const float* vb = qkv + (size_t)b * O3 * N + (size_t)(2 * HID + h * DH) * N + j0;
    for (int idx = t; idx < DH * JC; idx += 256) {
        int r = idx >> 7, j = idx & (JC - 1);
        ks[r][j] = kb[(size_t)r * N + j];
        vs[r][j] = vb[(size_t)r * N + j];
    }
    __syncthreads();

    const int e = t >> 3, d0 = (t & 7) * 4;
    float a0 = 0, a1 = 0, a2 = 0, a3 = 0;
    #pragma unroll 8
    for (int j = 0; j < JC; ++j) {
        float kv = ks[e][j];
        a0 += kv * vs[d0][j];
        a1 += kv * vs[d0 + 1][j];
        a2 += kv * vs[d0 + 2][j];
        a3 += kv * vs[d0 + 3][j];
    }
    float4 r4 = make_float4(a0, a1, a2, a3);
    ((float4*)(mpart + (size_t)((b * NH + h) * NCH + ch) * 1024))[t] = r4;
}

// ---------------- K2b: reduce M partials, fold with w_out -> U ----------------
// U[b][o][h*32+e] = sum_d w_out[o][h*32+d] * M[b,h,e,d]. grid: B*NH blocks.
__global__ __launch_bounds__(256) void k2b_fold_u(
    const float* __restrict__ mpart, const float* __restrict__ wout,
    float* __restrict__ U)
{
    __shared__ float Ms[DH][DH + 1];
    const int t = threadIdx.x;
    const int bx = blockIdx.x; /* b*NH + h */
    const int b = bx / NH, h = bx % NH;

    const float* mp = mpart + (size_t)bx * NCH * 1024;
    float a0 = 0, a1 = 0, a2 = 0, a3 = 0;
    for (int ch = 0; ch < NCH; ++ch) {
        float4 m4 = ((const float4*)(mp + (size_t)ch * 1024))[t];
        a0 += m4.x; a1 += m4.y; a2 += m4.z; a3 += m4.w;
    }
    {
        int e = t >> 3, d0 = (t & 7) * 4;
        Ms[e][d0] = a0; Ms[e][d0 + 1] = a1; Ms[e][d0 + 2] = a2; Ms[e][d0 + 3] = a3;
    }
    __syncthreads();

    #pragma unroll
    for (int it = 0; it < 8; ++it) {
        int idx = t + it * 256;
        int o = idx >> 5, e2 = idx & 31;
        float acc = 0.f;
        #pragma unroll
        for (int d = 0; d < DH; ++d)
            acc += wout[(size_t)o * HID + h * DH + d] * Ms[e2][d];
        U[((size_t)b * C + o) * HID + h * DH + e2] = acc;
    }
}

// ---------------- K3: out = U @ q + b_out + x ----------------
// grid: B * (N/TP) = 256 blocks of 256.
__global__ __launch_bounds__(256) void k3_final(
    const float* __restrict__ qkv, const float* __restrict__ U,
    const float* __restrict__ bout, const float* __restrict__ x,
    float* __restrict__ out)
{
    __shared__ float qs[HID][TP + 1];
    const int t = threadIdx.x;
    const int bx = blockIdx.x;
    const int b = bx / (N / TP);
    const int p0 = (bx % (N / TP)) * TP;

    const float* qb = qkv + (size_t)b * O3 * N + p0; /* q = rows [0,128), pre-scaled */
    for (int idx = t; idx < HID * TP; idx += 256) {
        int c = idx >> 5, p = idx & (TP - 1);
        qs[c][p] = qb[(size_t)c * N + p];
    }
    __syncthreads();

    const int p = t & (TP - 1);
    const int o0 = (t >> 5) * 8;
    const float* Ub = U + (size_t)b * C * HID;
    const float* xb = x + (size_t)b * C * N + p0;
    float* ob = out + (size_t)b * C * N + p0;
    for (int o = o0; o < o0 + 8; ++o) {
        const float4* ur = (const float4*)(Ub + (size_t)o * HID);
        float acc = bout[o];
        #pragma unroll
        for (int c4 = 0; c4 < 32; ++c4) {
            float4 u4 = ur[c4];
            int c = c4 * 4;
            acc += u4.x * qs[c][p] + u4.y * qs[c + 1][p]
                 + u4.z * qs[c + 2][p] + u4.w * qs[c + 3][p];
        }
        ob[(size_t)o * N + p] = acc + xb[(size_t)o * N + p];
    }
}

extern "C" void kernel_launch(void* const* d_in, const int* in_sizes, int n_in,
                              void* d_out, int out_size, void* d_ws, size_t ws_size,
                              hipStream_t stream)
{
    const float* x    = (const float*)d_in[0];
    const float* g    = (const float*)d_in[1];
    const float* wqkv = (const float*)d_in[2];
    const float* wout = (const float*)d_in[3];
    const float* bout = (const float*)d_in[4];
    float* out = (float*)d_out;

    float* qkv   = (float*)d_ws;                        /* B*O3*N floats = 12.6 MB */
    float* mpart = qkv + (size_t)B * O3 * N;            /* B*NH*NCH*1024 = 1 MB    */
    float* U     = mpart + (size_t)B * NH * NCH * 1024; /* B*C*HID = 64 KB         */

    k1_rmsnorm_qkv<<<B * (N / TP), 256, 0, stream>>>(x, g, wqkv, qkv);
    k2_kv_outer<<<B * NH * NCH, 256, 0, stream>>>(qkv, mpart);
    k2b_fold_u<<<B * NH, 256, 0, stream>>>(mpart, wout, U);
    k3_final<<<B * (N / TP), 256, 0, stream>>>(qkv, U, bout, x, out);
}

// Round 3
// 96.815 us; speedup vs baseline: 1.4822x; 1.4822x over previous
//
#include <hip/hip_runtime.h>
#include <math.h>

#define B 2
#define C 64
#define N 4096
#define O3 384
#define HID 128
#define NH 4
#define DH 32
#define JC 128
#define NCH (N / JC)   /* 32 */
#define PB 64          /* positions per block (K1/K3) */

#define SCALE 0.17677669529663687f /* 32^-0.5 */

// ---------------- K1: RMSNorm + QKV projection, o-split ----------------
// grid: 12 o-blocks x (B*N/PB = 128) pos-blocks = 1536 blocks of 256.
// Block: 64 positions x 32 outputs. Thread: 1 position x 8 outputs.
__global__ __launch_bounds__(256) void k1_rmsnorm_qkv(
    const float* __restrict__ x, const float* __restrict__ g,
    const float* __restrict__ wqkv, float* __restrict__ qkv)
{
    __shared__ float xs[C][PB + 1];
    __shared__ float part[4][PB];
    __shared__ float scale_s[PB];
    __shared__ float gs[C];

    const int t = threadIdx.x;
    const int bx = blockIdx.x;
    const int ob = bx / 128;          /* 0..11: output block (32 outs) */
    const int pblk = bx % 128;
    const int b = pblk >> 6;
    const int p0 = (pblk & 63) * PB;

    /* stage x tile [64c][64p] */
    const float* xb = x + (size_t)b * C * N + p0;
    #pragma unroll
    for (int it = 0; it < 4; ++it) {
        int idx = t + it * 256;              /* 1024 float4 = 64 rows x 16 */
        int row = idx >> 4, c4 = (idx & 15) * 4;
        float4 v4 = *(const float4*)(xb + (size_t)row * N + c4);
        xs[row][c4] = v4.x; xs[row][c4 + 1] = v4.y;
        xs[row][c4 + 2] = v4.z; xs[row][c4 + 3] = v4.w;
    }
    if (t < C) gs[t] = g[t];
    __syncthreads();

    /* norm per position (cheap, redone per o-block) */
    {
        int p = t & 63, cg = t >> 6;         /* 4 groups x 16 channels */
        float s = 0.f;
        #pragma unroll
        for (int c = 0; c < 16; ++c) { float v_ = xs[cg * 16 + c][p]; s += v_ * v_; }
        part[cg][p] = s;
    }
    __syncthreads();
    if (t < PB) {
        float ss = part[0][t] + part[1][t] + part[2][t] + part[3][t];
        scale_s[t] = 8.0f / fmaxf(sqrtf(ss), 1e-12f); /* sqrt(C)=8, torch eps */
    }
    __syncthreads();
    #pragma unroll
    for (int it = 0; it < 16; ++it) {        /* apply scale*g in LDS */
        int idx = t + it * 256;
        int c = idx >> 6, p = idx & 63;
        xs[c][p] *= scale_s[p] * gs[c];
    }
    __syncthreads();

    /* 8 outputs per thread; weights via wave-uniform scalar loads */
    const int p = t & 63;
    const int og = __builtin_amdgcn_readfirstlane(t >> 6); /* 0..3, wave-uniform */
    const int obase = ob * 32 + og * 8;
    float acc[8] = {0,0,0,0,0,0,0,0};
    #pragma unroll
    for (int c4 = 0; c4 < 16; ++c4) {
        const float xv0 = xs[c4 * 4 + 0][p];
        const float xv1 = xs[c4 * 4 + 1][p];
        const float xv2 = xs[c4 * 4 + 2][p];
        const float xv3 = xs[c4 * 4 + 3][p];
        #pragma unroll
        for (int k = 0; k < 8; ++k) {
            const float4 w4 = *(const float4*)(wqkv + (size_t)(obase + k) * C + c4 * 4);
            acc[k] += w4.x * xv0 + w4.y * xv1 + w4.z * xv2 + w4.w * xv3;
        }
    }
    const float qs = (obase < HID) ? SCALE : 1.0f; /* q rows pre-scaled */
    float* outb = qkv + (size_t)b * O3 * N + p0 + p;
    #pragma unroll
    for (int k = 0; k < 8; ++k)
        outb[(size_t)(obase + k) * N] = acc[k] * qs;
}

// ---------------- K2: partial M = K V^T per (b, h, j-chunk) ----------------
// grid: B*NH*NCH = 256 blocks of 256. Thread t -> M[e][d0..d0+3].
__global__ __launch_bounds__(256) void k2_kv_outer(
    const float* __restrict__ qkv, float* __restrict__ mpart)
{
    __shared__ float ks[DH][JC + 4];
    __shared__ float vs[DH][JC + 4];
    const int t = threadIdx.x;
    const int bx = blockIdx.x;
    const int b = bx / (NH * NCH);
    const int rem = bx % (NH * NCH);
    const int h = rem / NCH, ch = rem % NCH;
    const int j0 = ch * JC;

    const float* kb = qkv + (size_t)b * O3 * N + (size_t)(HID + h * DH) * N + j0;
    const float* vb = qkv + (size_t)b * O3 * N + (size_t)(2 * HID + h * DH) * N + j0;
    #pragma unroll
    for (int it = 0; it < 4; ++it) {         /* 1024 float4 per tensor */
        int idx = t + it * 256;
        int row = idx >> 5, c4 = (idx & 31) * 4;
        *(float4*)&ks[row][c4] = *(const float4*)(kb + (size_t)row * N + c4);
        *(float4*)&vs[row][c4] = *(const float4*)(vb + (size_t)row * N + c4);
    }
    __syncthreads();

    const int e = t >> 3, d0 = (t & 7) * 4;
    float a0 = 0, a1 = 0, a2 = 0, a3 = 0;
    #pragma unroll 8
    for (int j4 = 0; j4 < JC / 4; ++j4) {
        const float4 kk = *(const float4*)&ks[e][j4 * 4];
        const float4 v0 = *(const float4*)&vs[d0 + 0][j4 * 4];
        const float4 v1 = *(const float4*)&vs[d0 + 1][j4 * 4];
        const float4 v2 = *(const float4*)&vs[d0 + 2][j4 * 4];
        const float4 v3 = *(const float4*)&vs[d0 + 3][j4 * 4];
        a0 += kk.x * v0.x + kk.y * v0.y + kk.z * v0.z + kk.w * v0.w;
        a1 += kk.x * v1.x + kk.y * v1.y + kk.z * v1.z + kk.w * v1.w;
        a2 += kk.x * v2.x + kk.y * v2.y + kk.z * v2.z + kk.w * v2.w;
        a3 += kk.x * v3.x + kk.y * v3.y + kk.z * v3.z + kk.w * v3.w;
    }
    ((float4*)(mpart + (size_t)((b * NH + h) * NCH + ch) * 1024))[t] =
        make_float4(a0, a1, a2, a3);
}

// ---------------- K2b: reduce M partials + fold w_out -> U ----------------
// grid: B*NH*4 = 32 blocks of 256 (e-quarters).
__global__ __launch_bounds__(256) void k2b_fold_u(
    const float* __restrict__ mpart, const float* __restrict__ wout,
    float* __restrict__ U)
{
    __shared__ float Ms[8][DH + 1];
    const int t = threadIdx.x;
    const int bx = blockIdx.x;
    const int eq = bx & 3;                   /* e-quarter: e in [eq*8, eq*8+8) */
    const int bh = bx >> 2;                  /* b*NH + h */
    const int b = bh / NH, h = bh % NH;

    const float* mp = mpart + (size_t)bh * NCH * 1024 + eq * 256;
    float acc = 0.f;
    #pragma unroll 8
    for (int ch = 0; ch < NCH; ++ch)
        acc += mp[(size_t)ch * 1024 + t];
    Ms[t >> 5][t & 31] = acc;
    __syncthreads();

    /* fold: U[o][h*32 + eq*8 + er] = sum_d wout[o][h*32+d] * Ms[er][d] */
    #pragma unroll
    for (int half = 0; half < 2; ++half) {
        int u = t + half * 256;              /* 512 outputs: o=u&63, er=u>>6 */
        int o = u & 63, er = u >> 6;
        float s = 0.f;
        #pragma unroll
        for (int d4 = 0; d4 < 8; ++d4) {
            const float4 w4 = *(const float4*)(wout + (size_t)o * HID + h * DH + d4 * 4);
            s += w4.x * Ms[er][d4 * 4 + 0] + w4.y * Ms[er][d4 * 4 + 1]
               + w4.z * Ms[er][d4 * 4 + 2] + w4.w * Ms[er][d4 * 4 + 3];
        }
        U[((size_t)b * C + o) * HID + h * DH + eq * 8 + er] = s;
    }
}

// ---------------- K3: out = U @ q + b_out + x, o-split ----------------
// grid: 4 o-blocks x 128 pos-blocks = 512 blocks of 256.
// Block: 64 positions x 16 outputs. Thread: 1 position x 4 outputs.
__global__ __launch_bounds__(256) void k3_final(
    const float* __restrict__ qkv, const float* __restrict__ U,
    const float* __restrict__ bout, const float* __restrict__ x,
    float* __restrict__ out)
{
    __shared__ float qs[HID][PB + 1];
    const int t = threadIdx.x;
    const int bx = blockIdx.x;
    const int ob = bx / 128;                 /* 0..3: 16 outputs each */
    const int pblk = bx % 128;
    const int b = pblk >> 6;
    const int p0 = (pblk & 63) * PB;

    const float* qb = qkv + (size_t)b * O3 * N + p0; /* q rows, pre-scaled */
    #pragma unroll
    for (int it = 0; it < 8; ++it) {         /* 2048 float4 = 128 rows x 16 */
        int idx = t + it * 256;
        int row = idx >> 4, c4 = (idx & 15) * 4;
        float4 v4 = *(const float4*)(qb + (size_t)row * N + c4);
        qs[row][c4] = v4.x; qs[row][c4 + 1] = v4.y;
        qs[row][c4 + 2] = v4.z; qs[row][c4 + 3] = v4.w;
    }
    __syncthreads();

    const int p = t & 63;
    const int og = __builtin_amdgcn_readfirstlane(t >> 6); /* wave-uniform */
    const int o0 = ob * 16 + og * 4;
    const float* Ub = U + ((size_t)b * C + o0) * HID;
    float a0 = bout[o0], a1 = bout[o0 + 1], a2 = bout[o0 + 2], a3 = bout[o0 + 3];
    #pragma unroll
    for (int c4 = 0; c4 < 32; ++c4) {
        const float q0 = qs[c4 * 4 + 0][p];
        const float q1 = qs[c4 * 4 + 1][p];
        const float q2 = qs[c4 * 4 + 2][p];
        const float q3 = qs[c4 * 4 + 3][p];
        const float4 u0 = *(const float4*)(Ub + 0 * HID + c4 * 4);
        const float4 u1 = *(const float4*)(Ub + 1 * HID + c4 * 4);
        const float4 u2 = *(const float4*)(Ub + 2 * HID + c4 * 4);
        const float4 u3 = *(const float4*)(Ub + 3 * HID + c4 * 4);
        a0 += u0.x * q0 + u0.y * q1 + u0.z * q2 + u0.w * q3;
        a1 += u1.x * q0 + u1.y * q1 + u1.z * q2 + u1.w * q3;
        a2 += u2.x * q0 + u2.y * q1 + u2.z * q2 + u2.w * q3;
        a3 += u3.x * q0 + u3.y * q1 + u3.z * q2 + u3.w * q3;
    }
    const float* xb = x + ((size_t)b * C + o0) * N + p0 + p;
    float* ob_ = out + ((size_t)b * C + o0) * N + p0 + p;
    ob_[0 * N] = a0 + xb[0 * N];
    ob_[1 * N] = a1 + xb[1 * N];
    ob_[2 * N] = a2 + xb[2 * N];
    ob_[3 * N] = a3 + xb[3 * N];
}

extern "C" void kernel_launch(void* const* d_in, const int* in_sizes, int n_in,
                              void* d_out, int out_size, void* d_ws, size_t ws_size,
                              hipStream_t stream)
{
    const float* x    = (const float*)d_in[0];
    const float* g    = (const float*)d_in[1];
    const float* wqkv = (const float*)d_in[2];
    const float* wout = (const float*)d_in[3];
    const float* bout = (const float*)d_in[4];
    float* out = (float*)d_out;

    float* qkv   = (float*)d_ws;                        /* 12.58 MB */
    float* mpart = qkv + (size_t)B * O3 * N;            /* 1.05 MB  */
    float* U     = mpart + (size_t)B * NH * NCH * 1024; /* 65 KB    */

    k1_rmsnorm_qkv<<<12 * 128, 256, 0, stream>>>(x, g, wqkv, qkv);
    k2_kv_outer<<<B * NH * NCH, 256, 0, stream>>>(qkv, mpart);
    k2b_fold_u<<<B * NH * 4, 256, 0, stream>>>(mpart, wout, U);
    k3_final<<<4 * 128, 256, 0, stream>>>(qkv, U, bout, x, out);
}